// Round 5
// baseline (417.018 us; speedup 1.0000x reference)
//
#include <hip/hip_runtime.h>
#include <hip/hip_fp16.h>

#define BATCH 4096
#define F 39
#define E 16
#define ROW_F4 (F * E / 4)           // 156 float4 per gathered row (2496 B contiguous)
#define TOT_F4 (F * ROW_F4)          // 6084 float4 staged per batch row
#define NPAIRS (F * (F - 1))         // 1482 ordered pairs i != j
#define NTASK2 (NPAIRS * 2)          // 2964 (2 lanes per pair)
#define BLOCK 1024
#define NWAVES (BLOCK / 64)          // 16
#define GRID 512                     // 2 blocks/CU, persistent
#define ROWS (BATCH / GRID)          // 8 batch rows per block
#define SITER 6                      // ceil(6084 / 1024)
#define CITER 3                      // ceil(2964 / 1024)

// 48.7 KB LDS tile + 2.5 KB idx/vals -> 2 blocks/CU (32 waves). (1024,8) caps VGPR at 64.
__global__ __launch_bounds__(BLOCK, 8) void ffm_kernel(
    const int*   __restrict__ idx,    // [B, F]
    const float* __restrict__ vals,   // [B, F]
    const float* __restrict__ emb,    // [100000, F, E]
    const float* __restrict__ w1,     // [100000, 1]
    const float* __restrict__ bias,   // [1]
    float*       __restrict__ out)    // [B, 1]
{
    const int tid = threadIdx.x;
    const int b0  = blockIdx.x * ROWS;

    __shared__ __align__(16) __half s_emb[F * F * E];   // 48672 B, single buffer
    __shared__ int   s_idx[ROWS][F];
    __shared__ float s_val[ROWS][F];
    __shared__ float s_red[NWAVES];

    // ---- Prologue: idx/vals for all 8 rows ----
    if (tid < ROWS * F) {
        ((int*)s_idx)[tid]   = idx[b0 * F + tid];
        ((float*)s_val)[tid] = vals[b0 * F + tid];
    }
    __syncthreads();

    // Per-thread staging coords, constant across rounds: t = tid + k*BLOCK
    // ci = t/156 (which field row), coff = t%156 (float4 within row). Packed.
    int cpk[SITER];
    #pragma unroll
    for (int k = 0; k < SITER; ++k) {
        int t  = tid + k * BLOCK;
        int tc = t < TOT_F4 ? t : TOT_F4 - 1;    // clamp (dup load benign, write skipped)
        int ci = tc / ROW_F4;
        cpk[k] = (ci << 16) | (tc - ci * ROW_F4);
    }

    const float4* emb4 = (const float4*)emb;
    __half2* s2 = (__half2*)s_emb;
    float4 g[SITER];

    // ---- Stage row 0 ----
    #pragma unroll
    for (int k = 0; k < SITER; ++k)
        g[k] = emb4[s_idx[0][cpk[k] >> 16] * ROW_F4 + (cpk[k] & 0xffff)];
    #pragma unroll
    for (int k = 0; k < SITER; ++k) {
        int t = tid + k * BLOCK;
        if (t < TOT_F4) {
            s2[t * 2]     = __floats2half2_rn(g[k].x, g[k].y);
            s2[t * 2 + 1] = __floats2half2_rn(g[k].z, g[k].w);
        }
    }
    __syncthreads();

    for (int r = 0; r < ROWS; ++r) {
        // ---- Prefetch row r+1 gathers into registers (latency overlapped below) ----
        if (r + 1 < ROWS) {
            #pragma unroll
            for (int k = 0; k < SITER; ++k)
                g[k] = emb4[s_idx[r + 1][cpk[k] >> 16] * ROW_F4 + (cpk[k] & 0xffff)];
        }

        // ---- Compute row r pairs from LDS: ordered (i,j) i!=j, 0.5x; 2 lanes/pair ----
        float acc = 0.0f;
        if (tid < F) acc = s_val[r][tid] * w1[s_idx[r][tid]];   // first-order

        #pragma unroll
        for (int it = 0; it < CITER; ++it) {
            int t = tid + it * BLOCK;
            if (t < NTASK2) {
                int p = t >> 1;
                int h = t & 1;
                int i = p / (F - 1);
                int q = p - i * (F - 1);
                int j = q + (q >= i ? 1 : 0);
                float4 av = *(const float4*)&s_emb[(i * F + j) * E + h * 8];
                float4 cv = *(const float4*)&s_emb[(j * F + i) * E + h * 8];
                const __half2* ah = (const __half2*)&av;
                const __half2* ch = (const __half2*)&cv;
                float dot = 0.0f;
                #pragma unroll
                for (int k = 0; k < 4; ++k) {
                    float2 a = __half22float2(ah[k]);
                    float2 c = __half22float2(ch[k]);
                    dot += a.x * c.x + a.y * c.y;
                }
                acc += dot * (0.5f * s_val[r][i] * s_val[r][j]);
            }
        }

        // ---- Reduce ----
        #pragma unroll
        for (int off = 32; off > 0; off >>= 1)
            acc += __shfl_down(acc, off, 64);
        if ((tid & 63) == 0) s_red[tid >> 6] = acc;
        __syncthreads();                       // buf free + s_red ready

        if (tid == 0) {
            float s = 0.0f;
            #pragma unroll
            for (int w = 0; w < NWAVES; ++w) s += s_red[w];
            out[b0 + r] = s + bias[0];
        }

        // ---- Write staged row r+1 into the (now free) buffer ----
        if (r + 1 < ROWS) {
            #pragma unroll
            for (int k = 0; k < SITER; ++k) {
                int t = tid + k * BLOCK;
                if (t < TOT_F4) {
                    s2[t * 2]     = __floats2half2_rn(g[k].x, g[k].y);
                    s2[t * 2 + 1] = __floats2half2_rn(g[k].z, g[k].w);
                }
            }
            __syncthreads();                   // buf staged for next round
        }
    }
}

extern "C" void kernel_launch(void* const* d_in, const int* in_sizes, int n_in,
                              void* d_out, int out_size, void* d_ws, size_t ws_size,
                              hipStream_t stream) {
    const int*   idx  = (const int*)d_in[0];
    const float* vals = (const float*)d_in[1];
    const float* emb  = (const float*)d_in[2];
    const float* w1   = (const float*)d_in[3];
    const float* bias = (const float*)d_in[4];
    float* out = (float*)d_out;

    ffm_kernel<<<GRID, BLOCK, 0, stream>>>(idx, vals, emb, w1, bias, out);
}